// Round 1
// baseline (370.003 us; speedup 1.0000x reference)
//
#include <hip/hip_runtime.h>

// DetectionLayer: (32, 255, 76, 76) f32 -> (32, 76*76*3, 85) f32
// c = box*85 + attr; out[(b, (h*76+w)*3+box, attr)]
//
// attr 0: cx = (sigmoid(v)*1.05 - 0.025 + w)/76
// attr 1: cy = (sigmoid(v)*1.05 - 0.025 + h)/76
// attr 2: hw = exp(v)*anchor_w/(2*608)
// attr 3: hh = exp(v)*anchor_h/(2*608)
// out0 = cx-hw, out1 = cy-hh, out2 = cx+hw, out3 = cy+hh
// attr 4..84: sigmoid(v)

#define NUM_ATTRS 85
#define HWSZ 5776            // 76*76
#define TILE 128             // spatial positions per block
#define NTILES 46            // ceil(5776/128)
#define LDS_STRIDE (TILE + 1) // 129 ≡ 1 (mod 32) -> conflict-free write-phase reads

__device__ __forceinline__ float fsigmoid(float x) {
    return 1.0f / (1.0f + __expf(-x));
}

__global__ __launch_bounds__(256) void detect_kernel(const float* __restrict__ in,
                                                     float* __restrict__ out) {
    __shared__ float tile[NUM_ATTRS * LDS_STRIDE];

    const int tix = blockIdx.x;   // spatial tile
    const int box = blockIdx.y;   // 0..2
    const int b   = blockIdx.z;   // 0..31
    const int tid = threadIdx.x;

    const int s0   = tix * TILE;
    const int npos = min(TILE, HWSZ - s0);   // 128 or 16 (tail)
    const int n4   = npos >> 2;

    // 0.5 * anchor / 608
    const float awk[3] = {10.0f / 1216.0f, 16.0f / 1216.0f, 33.0f / 1216.0f};
    const float ahk[3] = {13.0f / 1216.0f, 30.0f / 1216.0f, 23.0f / 1216.0f};
    const float aw = awk[box];
    const float ah = ahk[box];

    const float* __restrict__ src = in + ((size_t)b * 255 + (size_t)box * 85) * HWSZ;

    // ---- load phase: coalesced float4 reads, per-attr transform, store to LDS ----
    for (int i = tid; i < NUM_ATTRS * (TILE >> 2); i += 256) {
        const int attr = i >> 5;      // row
        const int c4   = i & 31;      // float4 column
        if (c4 < n4) {
            const int pos = s0 + c4 * 4;
            const float4 v = *reinterpret_cast<const float4*>(src + (size_t)attr * HWSZ + pos);
            float r[4] = {v.x, v.y, v.z, v.w};
#pragma unroll
            for (int j = 0; j < 4; ++j) {
                const int p = pos + j;
                const float x = r[j];
                float o;
                if (attr == 0) {
                    const float w = (float)(p % 76);
                    o = (fsigmoid(x) * 1.05f - 0.025f + w) * (1.0f / 76.0f);
                } else if (attr == 1) {
                    const float h = (float)(p / 76);
                    o = (fsigmoid(x) * 1.05f - 0.025f + h) * (1.0f / 76.0f);
                } else if (attr == 2) {
                    o = __expf(x) * aw;
                } else if (attr == 3) {
                    o = __expf(x) * ah;
                } else {
                    o = fsigmoid(x);
                }
                tile[attr * LDS_STRIDE + c4 * 4 + j] = o;
            }
        }
    }
    __syncthreads();

    // ---- write phase: coalesced contiguous 85-float chunks per position ----
    // out flat = b*17328*85 + (s0+p)*255 + box*85 + attr
    float* __restrict__ dst = out + (size_t)b * (HWSZ * 3 * 85)
                                  + (size_t)s0 * 255 + (size_t)box * 85;
    const int total = npos * NUM_ATTRS;
    for (int i = tid; i < total; i += 256) {
        const int p    = i / 85;
        const int attr = i - p * 85;
        float v;
        if (attr < 4) {
            const int base = attr & 1;            // 0 -> x, 1 -> y
            const float c  = tile[base * LDS_STRIDE + p];
            const float hf = tile[(base + 2) * LDS_STRIDE + p];
            v = (attr < 2) ? (c - hf) : (c + hf);
        } else {
            v = tile[attr * LDS_STRIDE + p];
        }
        dst[(size_t)p * 255 + attr] = v;
    }
}

extern "C" void kernel_launch(void* const* d_in, const int* in_sizes, int n_in,
                              void* d_out, int out_size, void* d_ws, size_t ws_size,
                              hipStream_t stream) {
    const float* x = (const float*)d_in[0];
    float* out = (float*)d_out;
    dim3 grid(NTILES, 3, 32);
    detect_kernel<<<grid, 256, 0, stream>>>(x, out);
}

// Round 6
// 339.814 us; speedup vs baseline: 1.0888x; 1.0888x over previous
//
#include <hip/hip_runtime.h>

// DetectionLayer: (32, 255, 76, 76) f32 -> (32, 76*76*3, 85) f32
// c = box*85 + attr; out[(b, (h*76+w)*3+box, attr)]
//
// attr 0: cx = (sigmoid(v)*1.05 - 0.025 + w)/76
// attr 1: cy = (sigmoid(v)*1.05 - 0.025 + h)/76
// attr 2: hw = exp(v)*anchor_w/(2*608)
// attr 3: hh = exp(v)*anchor_h/(2*608)
// out0 = cx-hw, out1 = cy-hh, out2 = cx+hw, out3 = cy+hh
// attr 4..84: sigmoid(v)
//
// R2 kernel (resubmitted R3/R4/R5/R6 — infra timeouts, never benched):
// TILE 128 -> 64. LDS 44 KB -> 22.1 KB => 7 blocks/CU = 28 waves/CU
// (was 3 blocks = 12 waves, Occupancy 31%). Latency-bound fix.
// Stride 65 + 16-lane attr rows => load-phase LDS writes only 2-way
// aliased (free), write-phase reads conflict-free.

#define NUM_ATTRS 85
#define HWSZ 5776             // 76*76
#define TILE 64               // spatial positions per block
#define NTILES 91             // ceil(5776/64): 90 full + tail 16
#define LDS_STRIDE (TILE + 1) // 65 == 1 (mod 32)

__device__ __forceinline__ float fsigmoid(float x) {
    return 1.0f / (1.0f + __expf(-x));
}

__global__ __launch_bounds__(256) void detect_kernel(const float* __restrict__ in,
                                                     float* __restrict__ out) {
    __shared__ float tile[NUM_ATTRS * LDS_STRIDE];

    const int tix = blockIdx.x;   // spatial tile
    const int box = blockIdx.y;   // 0..2
    const int b   = blockIdx.z;   // 0..31
    const int tid = threadIdx.x;

    const int s0   = tix * TILE;
    const int npos = min(TILE, HWSZ - s0);   // 64 or 16 (tail)
    const int n4   = npos >> 2;

    // 0.5 * anchor / 608
    const float awk[3] = {10.0f / 1216.0f, 16.0f / 1216.0f, 33.0f / 1216.0f};
    const float ahk[3] = {13.0f / 1216.0f, 30.0f / 1216.0f, 23.0f / 1216.0f};
    const float aw = awk[box];
    const float ah = ahk[box];

    const float* __restrict__ src = in + ((size_t)b * 255 + (size_t)box * 85) * HWSZ;

    // ---- load phase: coalesced float4 reads, per-attr transform, store to LDS ----
    // 85 rows x 16 float4s = 1360 items; 16 lanes per attr row.
#pragma unroll
    for (int it = 0; it < 6; ++it) {
        const int i = tid + it * 256;
        if (i < NUM_ATTRS * (TILE >> 2)) {
            const int attr = i >> 4;      // row
            const int c4   = i & 15;      // float4 column
            if (c4 < n4) {
                const int pos = s0 + c4 * 4;
                const float4 v = *reinterpret_cast<const float4*>(src + (size_t)attr * HWSZ + pos);
                float r[4] = {v.x, v.y, v.z, v.w};
#pragma unroll
                for (int j = 0; j < 4; ++j) {
                    const int p = pos + j;
                    const float x = r[j];
                    float o;
                    if (attr >= 4) {
                        o = fsigmoid(x);
                    } else if (attr == 0) {
                        const float w = (float)(p % 76);
                        o = (fsigmoid(x) * 1.05f - 0.025f + w) * (1.0f / 76.0f);
                    } else if (attr == 1) {
                        const float h = (float)(p / 76);
                        o = (fsigmoid(x) * 1.05f - 0.025f + h) * (1.0f / 76.0f);
                    } else if (attr == 2) {
                        o = __expf(x) * aw;
                    } else {
                        o = __expf(x) * ah;
                    }
                    tile[attr * LDS_STRIDE + c4 * 4 + j] = o;
                }
            }
        }
    }
    __syncthreads();

    // ---- write phase: coalesced contiguous 85-float chunks per position ----
    // out flat = b*17328*85 + (s0+p)*255 + box*85 + attr
    float* __restrict__ dst = out + (size_t)b * (HWSZ * 3 * 85)
                                  + (size_t)s0 * 255 + (size_t)box * 85;
    const int total = npos * NUM_ATTRS;   // 5440 or 1360
    for (int i = tid; i < total; i += 256) {
        const int p    = i / 85;
        const int attr = i - p * 85;
        float v;
        if (attr < 4) {
            const int base = attr & 1;            // 0 -> x, 1 -> y
            const float c  = tile[base * LDS_STRIDE + p];
            const float hf = tile[(base + 2) * LDS_STRIDE + p];
            v = (attr < 2) ? (c - hf) : (c + hf);
        } else {
            v = tile[attr * LDS_STRIDE + p];
        }
        dst[(size_t)p * 255 + attr] = v;
    }
}

extern "C" void kernel_launch(void* const* d_in, const int* in_sizes, int n_in,
                              void* d_out, int out_size, void* d_ws, size_t ws_size,
                              hipStream_t stream) {
    const float* x = (const float*)d_in[0];
    float* out = (float*)d_out;
    dim3 grid(NTILES, 3, 32);
    detect_kernel<<<grid, 256, 0, stream>>>(x, out);
}

// Round 8
// 308.193 us; speedup vs baseline: 1.2006x; 1.1026x over previous
//
#include <hip/hip_runtime.h>

// DetectionLayer: (32, 255, 76, 76) f32 -> (32, 76*76*3, 85) f32
// out[b][(h*76+w)*3+box][attr], input channel c = box*85+attr.
//
// attr0 = cx-hw, attr1 = cy-hh, attr2 = cx+hw, attr3 = cy+hh, attr4+ = sigmoid
//   cx = (sig(x)*1.05-0.025+w)/76, hw = exp(v)*anchor_w/1216 (= *0.5/608)
//
// R7 (resubmitted R8 — infra timeout, never benched):
// block = ALL 255 channels x 16 positions (5776 = 361*16, no tail).
//  - Output region per block = 16*255 contiguous floats, 16B-aligned base
//    -> phase 2 is a pure flat LDS->global float4 copy (no div, no branch).
//  - Box combination (cx +- hw) done in phase 1 by the rows-0/1 threads
//    (they also load rows 2/3); rows 2/3 threads idle. 6/255 rows special.
//  - LDS 16.3 KB -> 8 blocks/CU = 32 waves = 100% occupancy.
//  - Bijective XCD swizzle over 361 tiles (46 + 7*45) for L2 locality of
//    shared read lines / 64B-boundary write lines between adjacent tiles.

#define HWSZ 5776
#define TILE 16
#define NTILES 361            // 5776 / 16 exactly
#define NCH 255
#define LDS_DW (TILE * NCH)   // 4080 dwords = 16320 B

__device__ __forceinline__ float fsigmoid(float x) {
    return 1.0f / (1.0f + __expf(-x));
}

__global__ __launch_bounds__(256) void detect_kernel(const float* __restrict__ in,
                                                     float* __restrict__ out) {
    __shared__ float tile[LDS_DW];   // pos-major: tile[p_local*255 + c]

    // bijective XCD-aware swizzle: consecutive tiles -> same XCD
    const int x   = blockIdx.x;           // 0..360
    const int xcd = x & 7;
    const int idx = x >> 3;               // 0..45 (xcd 0) / 0..44 (others)
    const int tix = (xcd == 0 ? 0 : 46 + (xcd - 1) * 45) + idx;

    const int b   = blockIdx.y;
    const int tid = threadIdx.x;
    const int s0  = tix * TILE;

    const float* __restrict__ src = in + (size_t)b * NCH * HWSZ;

    // ---- phase 1: coalesced float4 reads (64B/row), transform, LDS pos-major ----
#pragma unroll
    for (int it = 0; it < 4; ++it) {
        const int i = tid + it * 256;
        if (i < NCH * (TILE / 4)) {       // 1020 items
            const int c   = i >> 2;       // channel 0..254
            const int c4  = i & 3;        // float4 column 0..3
            const int box = (c >= 170) ? 2 : (c >= 85 ? 1 : 0);
            const int sub = c - box * 85; // attr index
            const int pos = s0 + c4 * 4;  // global position of first elem

            if (sub >= 4) {
                const float4 v = *reinterpret_cast<const float4*>(src + (size_t)c * HWSZ + pos);
                const float r[4] = {v.x, v.y, v.z, v.w};
#pragma unroll
                for (int j = 0; j < 4; ++j)
                    tile[(c4 * 4 + j) * NCH + c] = fsigmoid(r[j]);
            } else if (sub < 2) {
                // sub==0: x-row (c) + w-row (c+2); sub==1: y-row + h-row
                float aw;
                if (sub == 0)
                    aw = (box == 0) ? 10.0f / 1216.0f : ((box == 1) ? 16.0f / 1216.0f : 33.0f / 1216.0f);
                else
                    aw = (box == 0) ? 13.0f / 1216.0f : ((box == 1) ? 30.0f / 1216.0f : 23.0f / 1216.0f);
                const float4 vx = *reinterpret_cast<const float4*>(src + (size_t)c * HWSZ + pos);
                const float4 vw = *reinterpret_cast<const float4*>(src + (size_t)(c + 2) * HWSZ + pos);
                const float rx[4] = {vx.x, vx.y, vx.z, vx.w};
                const float rw[4] = {vw.x, vw.y, vw.z, vw.w};
#pragma unroll
                for (int j = 0; j < 4; ++j) {
                    const int p  = pos + j;
                    const int ph = p / 76;
                    const float coord = (sub == 0) ? (float)(p - ph * 76) : (float)ph;
                    const float ctr  = (fsigmoid(rx[j]) * 1.05f - 0.025f + coord) * (1.0f / 76.0f);
                    const float half = __expf(rw[j]) * aw;
                    tile[(c4 * 4 + j) * NCH + c]     = ctr - half;   // attr sub
                    tile[(c4 * 4 + j) * NCH + c + 2] = ctr + half;   // attr sub+2
                }
            }
            // sub==2,3: handled by the sub-2 thread; idle.
        }
    }
    __syncthreads();

    // ---- phase 2: flat aligned LDS -> global vector copy ----
    // dst base dword = b*5776*255 + s0*255 ; s0*255*4 B is 16B-aligned.
    float* __restrict__ dst = out + (size_t)b * ((size_t)HWSZ * NCH) + (size_t)s0 * NCH;
#pragma unroll
    for (int it = 0; it < 4; ++it) {
        const int i = tid + it * 256;
        if (i < LDS_DW / 4) {             // 1020 float4s
            const float4 v = *reinterpret_cast<const float4*>(tile + 4 * i);
            *reinterpret_cast<float4*>(dst + 4 * i) = v;
        }
    }
}

extern "C" void kernel_launch(void* const* d_in, const int* in_sizes, int n_in,
                              void* d_out, int out_size, void* d_ws, size_t ws_size,
                              hipStream_t stream) {
    const float* x = (const float*)d_in[0];
    float* out = (float*)d_out;
    dim3 grid(NTILES, 32);
    detect_kernel<<<grid, 256, 0, stream>>>(x, out);
}